// Round 6
// baseline (106.188 us; speedup 1.0000x reference)
//
#include <hip/hip_runtime.h>
#include <stdint.h>

typedef float  f32x4v __attribute__((ext_vector_type(4)));
typedef short  s16x8  __attribute__((ext_vector_type(8)));

constexpr int D      = 64;    // feature dim (fixed by problem)
constexpr int SPLITS = 64;    // M-chunks; grid = (64, N/1024) = 512 blocks = 2/CU
constexpr int CHM    = 512;   // targets per chunk = M/SPLITS; chunk resident in LDS (64 KB exactly)
constexpr int G      = 8;     // source groups of 16 per wave -> 128 src/wave, 8 waves -> 1024/block

__device__ __forceinline__ unsigned short f2bf(float f) {
    // round-to-nearest-even fp32 -> bf16 (inputs are finite normals)
    unsigned int u = __float_as_uint(f);
    u = (u + 0x7FFFu + ((u >> 16) & 1u)) >> 16;
    return (unsigned short)u;
}

// async global->LDS DMA; LDS dest is wave-uniform base + lane*size (linear),
// swizzle applied on the per-lane GLOBAL source address instead.
__device__ __forceinline__ void gload_lds16(const void* g, void* l) {
    __builtin_amdgcn_global_load_lds((__attribute__((address_space(1))) void*)g,
                                     (__attribute__((address_space(3))) void*)l, 16, 0, 0);
}

// ---- fused prep (one launch):
//  blocks [0, M/16)            : Yb = bf16(Y),      t[m]  = ||y||^2 - psi[m]
//  blocks [M/16, M/16+N/16)    : Xb = bf16(-2*X),   sqx[n] = ||x||^2
//  blocks [.., +64)            : psi partial sums -> psum_arr[64]
__global__ __launch_bounds__(256)
void prep(const float* __restrict__ X, const float* __restrict__ Y,
          const float* __restrict__ psi,
          unsigned short* __restrict__ Xb, unsigned short* __restrict__ Yb,
          float* __restrict__ t, float* __restrict__ sqx,
          float* __restrict__ psum_arr, int N, int M) {
    const int tid  = threadIdx.x;
    const int lane = tid & 63, wave = tid >> 6;
    const int r16  = lane & 15, q = lane >> 4;
    const int NYB = M >> 4, NXB = N >> 4;
    const int b = blockIdx.x;
    __shared__ float red[4];

    if (b < NYB) {
        const int row = b * 16 + wave * 4 + q;
        const float4 v = *reinterpret_cast<const float4*>(Y + (size_t)row * D + r16 * 4);
        uint2 p;
        p.x = (unsigned)f2bf(v.x) | ((unsigned)f2bf(v.y) << 16);
        p.y = (unsigned)f2bf(v.z) | ((unsigned)f2bf(v.w) << 16);
        *reinterpret_cast<uint2*>(Yb + (size_t)row * D + r16 * 4) = p;
        float s = v.x * v.x + v.y * v.y + v.z * v.z + v.w * v.w;
        #pragma unroll
        for (int off = 1; off <= 8; off <<= 1) s += __shfl_xor(s, off);
        if (r16 == 0) t[row] = s - psi[row];
    } else if (b < NYB + NXB) {
        const int row = (b - NYB) * 16 + wave * 4 + q;
        const float4 v = *reinterpret_cast<const float4*>(X + (size_t)row * D + r16 * 4);
        uint2 p;   // store -2*x in bf16: cost = (||y||^2 - psi) + <-2x, y>
        p.x = (unsigned)f2bf(-2.f * v.x) | ((unsigned)f2bf(-2.f * v.y) << 16);
        p.y = (unsigned)f2bf(-2.f * v.z) | ((unsigned)f2bf(-2.f * v.w) << 16);
        *reinterpret_cast<uint2*>(Xb + (size_t)row * D + r16 * 4) = p;
        float s = v.x * v.x + v.y * v.y + v.z * v.z + v.w * v.w;
        #pragma unroll
        for (int off = 1; off <= 8; off <<= 1) s += __shfl_xor(s, off);
        if (r16 == 0) sqx[row] = s;
    } else {
        const int g = b - NYB - NXB;            // 0..63, M == 64*512
        float s = psi[g * 512 + tid] + psi[g * 512 + 256 + tid];
        #pragma unroll
        for (int off = 1; off <= 32; off <<= 1) s += __shfl_xor(s, off);
        if (lane == 0) red[wave] = s;
        __syncthreads();
        if (tid == 0) psum_arr[g] = red[0] + red[1] + red[2] + red[3];
    }
}

// ---- main: A = targets (LDS-resident full chunk), B = sources (registers),
// 16x16x32 bf16 MFMA. C/D: col=lane&15 -> SOURCE, row=(lane>>4)*4+r -> TARGET:
// min axis is in-register; tv = ||y||^2 - psi enters as the MFMA C-operand,
// read straight from global t (2 KB/chunk, L1-resident) - no lt in LDS.
// 512-thread blocks (8 waves), G=8: lean registers (~115 <= cap 128, no spill),
// 16 waves/CU = 4 waves/SIMD for cross-wave MFMA/VALU overlap. One barrier.
// Inner loop software-pipelined: st+1's a-frags + tv prefetched during st's
// 16 MFMAs, so ds_read/L1 latency hides under the MFMA burst.
__global__ __launch_bounds__(512, 4)
void sdot_main(const unsigned short* __restrict__ Xb,
               const unsigned short* __restrict__ Yb,
               const float* __restrict__ t,
               float* __restrict__ partial, int M) {
    __shared__ __align__(16) unsigned short ly[CHM * D];   // 65536 B exactly

    const int tid  = threadIdx.x;
    const int wave = tid >> 6, lane = tid & 63;
    const int quad = lane >> 4, r16 = lane & 15;
    const int chunk   = blockIdx.x;
    const int rowgrp  = blockIdx.y;
    const int m_begin = chunk * CHM;

    // 1) full-chunk DMA: 64 KB = 8 x 16B per thread (512 threads).
    //    source pre-swizzled so linear LDS slot c holds logical granule c^(row&7).
    #pragma unroll
    for (int i = 0; i < 8; ++i) {
        const int idx = i * 512 + tid;          // granule index (8 ushorts each)
        const int row = idx >> 3, c = idx & 7;
        gload_lds16(Yb + (size_t)(m_begin + row) * D + ((c ^ (row & 7)) << 3),
                    &ly[(i * 512 + wave * 64) << 3]);
    }

    // 2) B fragments (sources) into registers while the DMA flies.
    //    B[n=lane&15][k=quad*8+j], K-half h.  8 waves x 128 rows = 1024 rows/block.
    s16x8 b[G][2];
    #pragma unroll
    for (int g = 0; g < G; ++g) {
        const int srow = rowgrp * 1024 + wave * (G * 16) + g * 16 + r16;
        #pragma unroll
        for (int h = 0; h < 2; ++h)
            b[g][h] = *reinterpret_cast<const s16x8*>(Xb + (size_t)srow * D + h * 32 + quad * 8);
    }

    float rmin[G];
    #pragma unroll
    for (int g = 0; g < G; ++g) rmin[g] = 1e30f;

    // 3) the only barrier in the kernel
    asm volatile("s_waitcnt vmcnt(0)" ::: "memory");
    __builtin_amdgcn_s_barrier();

    // 4) 32 software-pipelined steps over the chunk.
    const int csw0 = (quad ^ (r16 & 7)) << 3;        // st-invariant swizzled cols
    const int csw1 = ((quad + 4) ^ (r16 & 7)) << 3;
    const float* tq = t + m_begin + quad * 4;        // tv rows for this lane

    s16x8  a0 = *reinterpret_cast<const s16x8*>(&ly[r16 * D + csw0]);
    s16x8  a1 = *reinterpret_cast<const s16x8*>(&ly[r16 * D + csw1]);
    f32x4v tv = *reinterpret_cast<const f32x4v*>(tq);

    for (int st = 0; st < CHM / 16; ++st) {
        // prefetch st+1 (wraps to 0 on last iter: harmless, keeps straight-line code)
        const int nst  = (st + 1) & (CHM / 16 - 1);
        const int trow = nst * 16 + r16;
        const s16x8  na0 = *reinterpret_cast<const s16x8*>(&ly[trow * D + csw0]);
        const s16x8  na1 = *reinterpret_cast<const s16x8*>(&ly[trow * D + csw1]);
        const f32x4v ntv = *reinterpret_cast<const f32x4v*>(tq + nst * 16);

        #pragma unroll
        for (int g = 0; g < G; g += 2) {   // 2 interleaved acc chains for MFMA ILP
            f32x4v p = __builtin_amdgcn_mfma_f32_16x16x32_bf16(a0, b[g    ][0], tv, 0, 0, 0);
            f32x4v q = __builtin_amdgcn_mfma_f32_16x16x32_bf16(a0, b[g + 1][0], tv, 0, 0, 0);
            p = __builtin_amdgcn_mfma_f32_16x16x32_bf16(a1, b[g    ][1], p, 0, 0, 0);
            q = __builtin_amdgcn_mfma_f32_16x16x32_bf16(a1, b[g + 1][1], q, 0, 0, 0);
            // p/q ARE the costs; balanced min3-fusable fold
            rmin[g]     = fminf(fminf(fminf(p[0], p[1]), fminf(p[2], p[3])), rmin[g]);
            rmin[g + 1] = fminf(fminf(fminf(q[0], q[1]), fminf(q[2], q[3])), rmin[g + 1]);
        }
        a0 = na0; a1 = na1; tv = ntv;
    }

    // min across the 4 row-block lane groups (lanes l, l^16, l^32, l^48 share col)
    #pragma unroll
    for (int off = 16; off <= 32; off <<= 1)
        #pragma unroll
        for (int g = 0; g < G; ++g)
            rmin[g] = fminf(rmin[g], __shfl_xor(rmin[g], off));

    if (quad == 0) {   // lanes 0..15: col n = r16
        #pragma unroll
        for (int g = 0; g < G; ++g) {
            const int row = rowgrp * 1024 + wave * (G * 16) + g * 16 + r16;
            partial[(size_t)row * SPLITS + chunk] = rmin[g];
        }
    }
}

// ---- finalize: out[n] = ||x_n||^2 + mean(psi) + min over SPLITS partials
__global__ __launch_bounds__(256)
void finalize(const float* __restrict__ sqx, const float* __restrict__ partial,
              const float* __restrict__ psum_arr, float* __restrict__ out, int M) {
    const int lane = threadIdx.x & 63, wave = threadIdx.x >> 6;
    const int row  = blockIdx.x * 4 + wave;
    float ps = psum_arr[lane];                 // 64 partial psi sums
    #pragma unroll
    for (int off = 1; off <= 32; off <<= 1) ps += __shfl_xor(ps, off);
    float pm = partial[(size_t)row * SPLITS + lane];   // SPLITS == 64
    #pragma unroll
    for (int off = 1; off <= 32; off <<= 1) pm = fminf(pm, __shfl_xor(pm, off));
    if (lane == 0) out[row] = sqx[row] + ps / (float)M + pm;
}

extern "C" void kernel_launch(void* const* d_in, const int* in_sizes, int n_in,
                              void* d_out, int out_size, void* d_ws, size_t ws_size,
                              hipStream_t stream) {
    const float* X   = (const float*)d_in[0];   // [N, 64]
    const float* Y   = (const float*)d_in[1];   // [M, 64]
    const float* psi = (const float*)d_in[2];   // [M]
    float* out = (float*)d_out;

    const int N = in_sizes[0] / D;   // 8192
    const int M = in_sizes[2];       // 32768

    char* ws = (char*)d_ws;
    unsigned short* Yb = (unsigned short*)ws;                  // M*64 bf16  (4 MB)
    size_t off = (size_t)M * D * sizeof(unsigned short);
    unsigned short* Xb = (unsigned short*)(ws + off);          // N*64 bf16  (1 MB)
    off += (size_t)N * D * sizeof(unsigned short);
    float* t = (float*)(ws + off);                             // M floats (128 KB)
    off += (size_t)M * sizeof(float);
    float* sqx = (float*)(ws + off);                           // N floats (32 KB)
    off += (size_t)N * sizeof(float);
    float* partial = (float*)(ws + off);                       // N*SPLITS (2 MB)
    off += (size_t)N * SPLITS * sizeof(float);
    float* psum_arr = (float*)(ws + off);                      // 64 floats

    prep<<<(M >> 4) + (N >> 4) + 64, 256, 0, stream>>>(X, Y, psi, Xb, Yb, t, sqx, psum_arr, N, M);
    // block = 8 waves x (G*16) rows = 1024 source rows  ->  grid.y = N / 1024
    sdot_main<<<dim3(SPLITS, N / 1024), 512, 0, stream>>>(Xb, Yb, t, partial, M);
    finalize<<<N / 4, 256, 0, stream>>>(sqx, partial, psum_arr, out, M);
}

// Round 7
// 103.868 us; speedup vs baseline: 1.0223x; 1.0223x over previous
//
#include <hip/hip_runtime.h>
#include <stdint.h>

typedef float  f32x4v __attribute__((ext_vector_type(4)));
typedef short  s16x8  __attribute__((ext_vector_type(8)));

constexpr int D      = 64;    // feature dim (fixed by problem)
constexpr int SPLITS = 128;   // M-chunks; chunk = 256 targets = 32 KB, LDS-resident
constexpr int CHM    = 256;   // targets per chunk = M/SPLITS
constexpr int G      = 4;     // source groups of 16 per wave -> 64 src/wave, 4 waves -> 256/block
constexpr int NT     = CHM / 16;  // 16 steps over the chunk

__device__ __forceinline__ unsigned short f2bf(float f) {
    // round-to-nearest-even fp32 -> bf16 (inputs are finite normals)
    unsigned int u = __float_as_uint(f);
    u = (u + 0x7FFFu + ((u >> 16) & 1u)) >> 16;
    return (unsigned short)u;
}

// async global->LDS DMA; LDS dest is wave-uniform base + lane*size (linear),
// swizzle applied on the per-lane GLOBAL source address instead.
__device__ __forceinline__ void gload_lds16(const void* g, void* l) {
    __builtin_amdgcn_global_load_lds((__attribute__((address_space(1))) void*)g,
                                     (__attribute__((address_space(3))) void*)l, 16, 0, 0);
}
__device__ __forceinline__ void gload_lds4(const void* g, void* l) {
    __builtin_amdgcn_global_load_lds((__attribute__((address_space(1))) void*)g,
                                     (__attribute__((address_space(3))) void*)l, 4, 0, 0);
}

// ---- fused prep (one launch):
//  blocks [0, M/16)            : Yb = bf16(Y),      t[m]  = ||y||^2 - psi[m]
//  blocks [M/16, M/16+N/16)    : Xb = bf16(-2*X),   sqx[n] = ||x||^2
//  blocks [.., +64)            : psi partial sums -> psum_arr[64]
__global__ __launch_bounds__(256)
void prep(const float* __restrict__ X, const float* __restrict__ Y,
          const float* __restrict__ psi,
          unsigned short* __restrict__ Xb, unsigned short* __restrict__ Yb,
          float* __restrict__ t, float* __restrict__ sqx,
          float* __restrict__ psum_arr, int N, int M) {
    const int tid  = threadIdx.x;
    const int lane = tid & 63, wave = tid >> 6;
    const int r16  = lane & 15, q = lane >> 4;
    const int NYB = M >> 4, NXB = N >> 4;
    const int b = blockIdx.x;
    __shared__ float red[4];

    if (b < NYB) {
        const int row = b * 16 + wave * 4 + q;
        const float4 v = *reinterpret_cast<const float4*>(Y + (size_t)row * D + r16 * 4);
        uint2 p;
        p.x = (unsigned)f2bf(v.x) | ((unsigned)f2bf(v.y) << 16);
        p.y = (unsigned)f2bf(v.z) | ((unsigned)f2bf(v.w) << 16);
        *reinterpret_cast<uint2*>(Yb + (size_t)row * D + r16 * 4) = p;
        float s = v.x * v.x + v.y * v.y + v.z * v.z + v.w * v.w;
        #pragma unroll
        for (int off = 1; off <= 8; off <<= 1) s += __shfl_xor(s, off);
        if (r16 == 0) t[row] = s - psi[row];
    } else if (b < NYB + NXB) {
        const int row = (b - NYB) * 16 + wave * 4 + q;
        const float4 v = *reinterpret_cast<const float4*>(X + (size_t)row * D + r16 * 4);
        uint2 p;   // store -2*x in bf16: cost = (||y||^2 - psi) + <-2x, y>
        p.x = (unsigned)f2bf(-2.f * v.x) | ((unsigned)f2bf(-2.f * v.y) << 16);
        p.y = (unsigned)f2bf(-2.f * v.z) | ((unsigned)f2bf(-2.f * v.w) << 16);
        *reinterpret_cast<uint2*>(Xb + (size_t)row * D + r16 * 4) = p;
        float s = v.x * v.x + v.y * v.y + v.z * v.z + v.w * v.w;
        #pragma unroll
        for (int off = 1; off <= 8; off <<= 1) s += __shfl_xor(s, off);
        if (r16 == 0) sqx[row] = s;
    } else {
        const int g = b - NYB - NXB;            // 0..63, M == 64*512
        float s = psi[g * 512 + tid] + psi[g * 512 + 256 + tid];
        #pragma unroll
        for (int off = 1; off <= 32; off <<= 1) s += __shfl_xor(s, off);
        if (lane == 0) red[wave] = s;
        __syncthreads();
        if (tid == 0) psum_arr[g] = red[0] + red[1] + red[2] + red[3];
    }
}

// ---- main: A = targets (32 KB LDS-resident chunk), B = sources (registers),
// 16x16x32 bf16 MFMA. C/D: col=lane&15 -> SOURCE, row=(lane>>4)*4+r -> TARGET:
// min axis in-register; tv = ||y||^2 - psi is the MFMA C-operand.
// 256-thread blocks (4 waves), G=4: ~96 VGPR (b 32 + accA/accB 32 + a/tv/rmin
// ~20 + addr) -> no spill under the 128 cap; 4 blocks/CU (132 KB LDS), 4 w/SIMD.
// DEFERRED FOLD (T15): step st's 8 MFMAs issue into one named acc set while the
// fmin fold consumes the OTHER set (completed a full step ago) -> the wave never
// stalls on MFMA latency. One barrier; free-running steps; setprio on MFMAs.
__global__ __launch_bounds__(256, 4)
void sdot_main(const unsigned short* __restrict__ Xb,
               const unsigned short* __restrict__ Yb,
               const float* __restrict__ t,
               float* __restrict__ partial, int M) {
    __shared__ __align__(16) unsigned short ly[CHM * D];   // 32 KB
    __shared__ __align__(16) float lt[CHM];                // 1 KB

    const int tid  = threadIdx.x;
    const int wave = tid >> 6, lane = tid & 63;
    const int quad = lane >> 4, r16 = lane & 15;
    const int chunk   = blockIdx.x;
    const int rowgrp  = blockIdx.y;
    const int m_begin = chunk * CHM;

    // 1) full-chunk DMA: 32 KB = 8 x 16B per thread; +1 x 4B for lt.
    //    Source pre-swizzled: linear LDS slot c holds logical granule c^(row&7).
    #pragma unroll
    for (int i = 0; i < 8; ++i) {
        const int idx = i * 256 + tid;          // granule index (8 ushorts each)
        const int row = idx >> 3, c = idx & 7;
        gload_lds16(Yb + (size_t)(m_begin + row) * D + ((c ^ (row & 7)) << 3),
                    &ly[(i * 256 + wave * 64) << 3]);
    }
    gload_lds4(t + m_begin + wave * 64 + lane, &lt[wave * 64]);

    // 2) B fragments (sources) into registers while the DMA flies.
    //    B[n=lane&15][k=quad*8+j], K-half h.  4 waves x 64 rows = 256 rows/block.
    s16x8 b[G][2];
    #pragma unroll
    for (int g = 0; g < G; ++g) {
        const int srow = rowgrp * 256 + wave * (G * 16) + g * 16 + r16;
        #pragma unroll
        for (int h = 0; h < 2; ++h)
            b[g][h] = *reinterpret_cast<const s16x8*>(Xb + (size_t)srow * D + h * 32 + quad * 8);
    }

    float rmin[G];
    #pragma unroll
    for (int g = 0; g < G; ++g) rmin[g] = 1e30f;

    // 3) the only barrier in the kernel
    asm volatile("s_waitcnt vmcnt(0)" ::: "memory");
    __builtin_amdgcn_s_barrier();

    const int csw0 = (quad ^ (r16 & 7)) << 3;        // st-invariant swizzled cols
    const int csw1 = ((quad + 4) ^ (r16 & 7)) << 3;

    // STEP: issue 8 MFMAs for step 'st' into acc set A_ (no reads of A_ after)
#define SDOT_STEP(st, A_)                                                           \
    {                                                                               \
        const int trow = (st) * 16 + r16;                                           \
        const s16x8 a0 = *reinterpret_cast<const s16x8*>(&ly[trow * D + csw0]);     \
        const s16x8 a1 = *reinterpret_cast<const s16x8*>(&ly[trow * D + csw1]);     \
        const f32x4v tv4 = *reinterpret_cast<const f32x4v*>(&lt[(st) * 16 + quad * 4]); \
        __builtin_amdgcn_s_setprio(1);                                              \
        _Pragma("unroll")                                                           \
        for (int g = 0; g < G; ++g)                                                 \
            A_[g] = __builtin_amdgcn_mfma_f32_16x16x32_bf16(a0, b[g][0], tv4, 0, 0, 0); \
        _Pragma("unroll")                                                           \
        for (int g = 0; g < G; ++g)                                                 \
            A_[g] = __builtin_amdgcn_mfma_f32_16x16x32_bf16(a1, b[g][1], A_[g], 0, 0, 0); \
        __builtin_amdgcn_s_setprio(0);                                              \
    }
    // FOLD: min-reduce a COMPLETED acc set into rmin (no MFMA-latency stall)
#define SDOT_FOLD(A_)                                                               \
    {                                                                               \
        _Pragma("unroll")                                                           \
        for (int g = 0; g < G; ++g)                                                 \
            rmin[g] = fminf(fminf(fminf(A_[g][0], A_[g][1]),                        \
                                  fminf(A_[g][2], A_[g][3])), rmin[g]);             \
    }

    f32x4v accA[G], accB[G];
    SDOT_STEP(0, accB);
    for (int p = 0; p < NT / 2 - 1; ++p) {       // steps 1 .. NT-2, ping-pong
        SDOT_STEP(2 * p + 1, accA);  SDOT_FOLD(accB);
        SDOT_STEP(2 * p + 2, accB);  SDOT_FOLD(accA);
    }
    SDOT_STEP(NT - 1, accA);  SDOT_FOLD(accB);  SDOT_FOLD(accA);
#undef SDOT_STEP
#undef SDOT_FOLD

    // min across the 4 row-block lane groups (lanes l, l^16, l^32, l^48 share col)
    #pragma unroll
    for (int off = 16; off <= 32; off <<= 1)
        #pragma unroll
        for (int g = 0; g < G; ++g)
            rmin[g] = fminf(rmin[g], __shfl_xor(rmin[g], off));

    if (quad == 0) {   // lanes 0..15: col n = r16
        #pragma unroll
        for (int g = 0; g < G; ++g) {
            const int row = rowgrp * 256 + wave * (G * 16) + g * 16 + r16;
            partial[(size_t)row * SPLITS + chunk] = rmin[g];
        }
    }
}

// ---- finalize: out[n] = ||x_n||^2 + mean(psi) + min over SPLITS partials
__global__ __launch_bounds__(256)
void finalize(const float* __restrict__ sqx, const float* __restrict__ partial,
              const float* __restrict__ psum_arr, float* __restrict__ out, int M) {
    const int lane = threadIdx.x & 63, wave = threadIdx.x >> 6;
    const int row  = blockIdx.x * 4 + wave;
    float ps = psum_arr[lane];                 // 64 partial psi sums
    #pragma unroll
    for (int off = 1; off <= 32; off <<= 1) ps += __shfl_xor(ps, off);
    // SPLITS == 128: two partials per lane
    float pm = fminf(partial[(size_t)row * SPLITS + lane],
                     partial[(size_t)row * SPLITS + 64 + lane]);
    #pragma unroll
    for (int off = 1; off <= 32; off <<= 1) pm = fminf(pm, __shfl_xor(pm, off));
    if (lane == 0) out[row] = sqx[row] + ps / (float)M + pm;
}

extern "C" void kernel_launch(void* const* d_in, const int* in_sizes, int n_in,
                              void* d_out, int out_size, void* d_ws, size_t ws_size,
                              hipStream_t stream) {
    const float* X   = (const float*)d_in[0];   // [N, 64]
    const float* Y   = (const float*)d_in[1];   // [M, 64]
    const float* psi = (const float*)d_in[2];   // [M]
    float* out = (float*)d_out;

    const int N = in_sizes[0] / D;   // 8192
    const int M = in_sizes[2];       // 32768

    char* ws = (char*)d_ws;
    unsigned short* Yb = (unsigned short*)ws;                  // M*64 bf16  (4 MB)
    size_t off = (size_t)M * D * sizeof(unsigned short);
    unsigned short* Xb = (unsigned short*)(ws + off);          // N*64 bf16  (1 MB)
    off += (size_t)N * D * sizeof(unsigned short);
    float* t = (float*)(ws + off);                             // M floats (128 KB)
    off += (size_t)M * sizeof(float);
    float* sqx = (float*)(ws + off);                           // N floats (32 KB)
    off += (size_t)N * sizeof(float);
    float* partial = (float*)(ws + off);                       // N*SPLITS (4 MB)
    off += (size_t)N * SPLITS * sizeof(float);
    float* psum_arr = (float*)(ws + off);                      // 64 floats

    prep<<<(M >> 4) + (N >> 4) + 64, 256, 0, stream>>>(X, Y, psi, Xb, Yb, t, sqx, psum_arr, N, M);
    // block = 4 waves x (G*16) rows = 256 source rows  ->  grid = (128, N/256)
    sdot_main<<<dim3(SPLITS, N / 256), 256, 0, stream>>>(Xb, Yb, t, partial, M);
    finalize<<<N / 4, 256, 0, stream>>>(sqx, partial, psum_arr, out, M);
}

// Round 9
// 103.086 us; speedup vs baseline: 1.0301x; 1.0076x over previous
//
#include <hip/hip_runtime.h>
#include <stdint.h>

typedef float  f32x4v __attribute__((ext_vector_type(4)));
typedef short  s16x8  __attribute__((ext_vector_type(8)));

constexpr int D      = 64;    // feature dim (fixed by problem)
constexpr int SPLITS = 32;    // M-chunks; grid = (32, N/256) = 1024 blocks = 4/CU exactly
constexpr int TILE_M = 128;   // targets staged in LDS per tile (double-buffered)
constexpr int G      = 4;     // source groups of 16 per wave -> 64 src/wave, 256/block

__device__ __forceinline__ unsigned short f2bf(float f) {
    // round-to-nearest-even fp32 -> bf16 (inputs are finite normals)
    unsigned int u = __float_as_uint(f);
    u = (u + 0x7FFFu + ((u >> 16) & 1u)) >> 16;
    return (unsigned short)u;
}

// async global->LDS DMA; LDS dest is wave-uniform base + lane*size (linear),
// swizzle applied on the per-lane GLOBAL source address instead.
__device__ __forceinline__ void gload_lds16(const void* g, void* l) {
    __builtin_amdgcn_global_load_lds((__attribute__((address_space(1))) void*)g,
                                     (__attribute__((address_space(3))) void*)l, 16, 0, 0);
}
__device__ __forceinline__ void gload_lds4(const void* g, void* l) {
    __builtin_amdgcn_global_load_lds((__attribute__((address_space(1))) void*)g,
                                     (__attribute__((address_space(3))) void*)l, 4, 0, 0);
}

// ---- fused prep (one launch):
//  blocks [0, M/16)            : Yb = bf16(Y),      t[m]  = ||y||^2 - psi[m]
//  blocks [M/16, M/16+N/16)    : Xb = bf16(-2*X),   sqx[n] = ||x||^2
//  blocks [.., +64)            : psi partial sums -> psum_arr[64]
__global__ __launch_bounds__(256)
void prep(const float* __restrict__ X, const float* __restrict__ Y,
          const float* __restrict__ psi,
          unsigned short* __restrict__ Xb, unsigned short* __restrict__ Yb,
          float* __restrict__ t, float* __restrict__ sqx,
          float* __restrict__ psum_arr, int N, int M) {
    const int tid  = threadIdx.x;
    const int lane = tid & 63, wave = tid >> 6;
    const int r16  = lane & 15, q = lane >> 4;
    const int NYB = M >> 4, NXB = N >> 4;
    const int b = blockIdx.x;
    __shared__ float red[4];

    if (b < NYB) {
        const int row = b * 16 + wave * 4 + q;
        const float4 v = *reinterpret_cast<const float4*>(Y + (size_t)row * D + r16 * 4);
        uint2 p;
        p.x = (unsigned)f2bf(v.x) | ((unsigned)f2bf(v.y) << 16);
        p.y = (unsigned)f2bf(v.z) | ((unsigned)f2bf(v.w) << 16);
        *reinterpret_cast<uint2*>(Yb + (size_t)row * D + r16 * 4) = p;
        float s = v.x * v.x + v.y * v.y + v.z * v.z + v.w * v.w;
        #pragma unroll
        for (int off = 1; off <= 8; off <<= 1) s += __shfl_xor(s, off);
        if (r16 == 0) t[row] = s - psi[row];
    } else if (b < NYB + NXB) {
        const int row = (b - NYB) * 16 + wave * 4 + q;
        const float4 v = *reinterpret_cast<const float4*>(X + (size_t)row * D + r16 * 4);
        uint2 p;   // store -2*x in bf16: cost = (||y||^2 - psi) + <-2x, y>
        p.x = (unsigned)f2bf(-2.f * v.x) | ((unsigned)f2bf(-2.f * v.y) << 16);
        p.y = (unsigned)f2bf(-2.f * v.z) | ((unsigned)f2bf(-2.f * v.w) << 16);
        *reinterpret_cast<uint2*>(Xb + (size_t)row * D + r16 * 4) = p;
        float s = v.x * v.x + v.y * v.y + v.z * v.z + v.w * v.w;
        #pragma unroll
        for (int off = 1; off <= 8; off <<= 1) s += __shfl_xor(s, off);
        if (r16 == 0) sqx[row] = s;
    } else {
        const int g = b - NYB - NXB;            // 0..63, M == 64*512
        float s = psi[g * 512 + tid] + psi[g * 512 + 256 + tid];
        #pragma unroll
        for (int off = 1; off <= 32; off <<= 1) s += __shfl_xor(s, off);
        if (lane == 0) red[wave] = s;
        __syncthreads();
        if (tid == 0) psum_arr[g] = red[0] + red[1] + red[2] + red[3];
    }
}

// ---- main: A = targets (LDS), B = sources (registers), 16x16x32 bf16 MFMA.
// R2's proven lockstep streaming structure (TILE_M=128 dbuf, stage->compute->
// vmcnt0->barrier per tile) upgraded with:
//  - G=4 + ping-pong accA/accB deferred fold -> ~95 VGPR, provably < 128 cap
//    under __launch_bounds__(256,4) in BOTH launch-bounds semantics (no spill).
//  - 34 KB LDS -> 4 blocks/CU -> 16 waves/CU = 4 waves/SIMD (2x R2's TLP).
//  - 8 tiles x 8 steps per block: prologue amortized (R7's 16-step blocks were not).
// C/D: col=lane&15 -> SOURCE, row=(lane>>4)*4+r -> TARGET: min axis in-register;
// tv = ||y||^2 - psi enters as the MFMA C-operand (one f32x4 ds_read).
__global__ __launch_bounds__(256, 4)
void sdot_main(const unsigned short* __restrict__ Xb,
               const unsigned short* __restrict__ Yb,
               const float* __restrict__ t,
               float* __restrict__ partial, int M) {
    __shared__ __align__(16) unsigned short ly[2][TILE_M * 64]; // 2 x 16 KB
    __shared__ __align__(16) float lt[2][256];                  // 2 x 1 KB (128 used)

    const int tid  = threadIdx.x;
    const int wave = tid >> 6, lane = tid & 63;
    const int quad = lane >> 4, r16 = lane & 15;
    const int chunk  = blockIdx.x;
    const int rowgrp = blockIdx.y;
    const int CH      = M / SPLITS;         // 1024
    const int m_begin = chunk * CH;
    const int NTT     = CH / TILE_M;        // 8 tiles

    // B fragments: sources in regs. B[n=lane&15][k=quad*8+j], K-half h.
    s16x8 b[G][2];
    #pragma unroll
    for (int g = 0; g < G; ++g) {
        const int srow = rowgrp * 256 + wave * (G * 16) + g * 16 + r16;
        #pragma unroll
        for (int h = 0; h < 2; ++h)
            b[g][h] = *reinterpret_cast<const s16x8*>(Xb + (size_t)srow * D + h * 32 + quad * 8);
    }

    float rmin[G];
    #pragma unroll
    for (int g = 0; g < G; ++g) rmin[g] = 1e30f;

    // stage one tile: 16 KB Yb (4 x 16B DMA/thread; source pre-swizzled so linear
    // LDS slot c holds logical granule c^(row&7)) + t values into lt.
    auto stage = [&](int buf, int mb) {
        #pragma unroll
        for (int i = 0; i < 4; ++i) {
            const int idx = i * 256 + tid;     // granule index (8 ushorts each)
            const int row = idx >> 3, c = idx & 7;
            gload_lds16(Yb + (size_t)(mb + row) * D + ((c ^ (row & 7)) << 3),
                        &ly[buf][(i * 256 + wave * 64) << 3]);
        }
        // waves 2,3 land in lt[128..255] (t over-read past M hits sqx region: harmless)
        gload_lds4(t + mb + wave * 64 + lane, &lt[buf][wave * 64]);
    };

    stage(0, m_begin);
    asm volatile("s_waitcnt vmcnt(0)" ::: "memory");
    __builtin_amdgcn_s_barrier();

    const int csw0 = (quad ^ (r16 & 7)) << 3;        // st-invariant swizzled cols
    const int csw1 = ((quad + 4) ^ (r16 & 7)) << 3;

    // STEP: issue 8 MFMAs for step 'st' of the current tile into acc set A_.
#define SDOT_STEP(st, A_)                                                           \
    {                                                                               \
        const int trow = (st) * 16 + r16;                                           \
        const s16x8 a0 = *reinterpret_cast<const s16x8*>(&ly[buf][trow * 64 + csw0]); \
        const s16x8 a1 = *reinterpret_cast<const s16x8*>(&ly[buf][trow * 64 + csw1]); \
        const f32x4v tv4 = *reinterpret_cast<const f32x4v*>(&lt[buf][(st) * 16 + quad * 4]); \
        __builtin_amdgcn_s_setprio(1);                                              \
        _Pragma("unroll")                                                           \
        for (int g = 0; g < G; ++g)                                                 \
            A_[g] = __builtin_amdgcn_mfma_f32_16x16x32_bf16(a0, b[g][0], tv4, 0, 0, 0); \
        _Pragma("unroll")                                                           \
        for (int g = 0; g < G; ++g)                                                 \
            A_[g] = __builtin_amdgcn_mfma_f32_16x16x32_bf16(a1, b[g][1], A_[g], 0, 0, 0); \
        __builtin_amdgcn_s_setprio(0);                                              \
    }
    // FOLD: min-reduce a COMPLETED acc set into rmin (issued a full step earlier)
#define SDOT_FOLD(A_)                                                               \
    {                                                                               \
        _Pragma("unroll")                                                           \
        for (int g = 0; g < G; ++g)                                                 \
            rmin[g] = fminf(fminf(fminf(A_[g][0], A_[g][1]),                        \
                                  fminf(A_[g][2], A_[g][3])), rmin[g]);             \
    }

    f32x4v accA[G], accB[G];
    for (int tI = 0; tI < NTT; ++tI) {
        const int buf = tI & 1;
        if (tI + 1 < NTT) stage(buf ^ 1, m_begin + (tI + 1) * TILE_M);

        // 8 steps over the tile, ping-pong deferred fold
        SDOT_STEP(0, accB);
        #pragma unroll
        for (int p = 0; p < 3; ++p) {            // steps 1..6
            SDOT_STEP(2 * p + 1, accA);  SDOT_FOLD(accB);
            SDOT_STEP(2 * p + 2, accB);  SDOT_FOLD(accA);
        }
        SDOT_STEP(7, accA);  SDOT_FOLD(accB);  SDOT_FOLD(accA);

        // next-tile DMA flew under the MFMAs; drain + barrier, swap buffers.
        asm volatile("s_waitcnt vmcnt(0)" ::: "memory");
        __builtin_amdgcn_s_barrier();
    }
#undef SDOT_STEP
#undef SDOT_FOLD

    // min across the 4 row-block lane groups (lanes l, l^16, l^32, l^48 share col)
    #pragma unroll
    for (int off = 16; off <= 32; off <<= 1)
        #pragma unroll
        for (int g = 0; g < G; ++g)
            rmin[g] = fminf(rmin[g], __shfl_xor(rmin[g], off));

    if (quad == 0) {   // lanes 0..15: col n = r16
        #pragma unroll
        for (int g = 0; g < G; ++g) {
            const int row = rowgrp * 256 + wave * (G * 16) + g * 16 + r16;
            partial[(size_t)row * SPLITS + chunk] = rmin[g];
        }
    }
}

// ---- finalize: out[n] = ||x_n||^2 + mean(psi) + min over SPLITS partials
__global__ __launch_bounds__(256)
void finalize(const float* __restrict__ sqx, const float* __restrict__ partial,
              const float* __restrict__ psum_arr, float* __restrict__ out, int M) {
    const int lane = threadIdx.x & 63, wave = threadIdx.x >> 6;
    const int row  = blockIdx.x * 4 + wave;
    float ps = psum_arr[lane];                 // 64 partial psi sums
    #pragma unroll
    for (int off = 1; off <= 32; off <<= 1) ps += __shfl_xor(ps, off);
    float pm = (lane < SPLITS) ? partial[(size_t)row * SPLITS + lane] : 1e30f;
    #pragma unroll
    for (int off = 1; off <= 32; off <<= 1) pm = fminf(pm, __shfl_xor(pm, off));
    if (lane == 0) out[row] = sqx[row] + ps / (float)M + pm;
}

extern "C" void kernel_launch(void* const* d_in, const int* in_sizes, int n_in,
                              void* d_out, int out_size, void* d_ws, size_t ws_size,
                              hipStream_t stream) {
    const float* X   = (const float*)d_in[0];   // [N, 64]
    const float* Y   = (const float*)d_in[1];   // [M, 64]
    const float* psi = (const float*)d_in[2];   // [M]
    float* out = (float*)d_out;

    const int N = in_sizes[0] / D;   // 8192
    const int M = in_sizes[2];       // 32768

    char* ws = (char*)d_ws;
    unsigned short* Yb = (unsigned short*)ws;                  // M*64 bf16  (4 MB)
    size_t off = (size_t)M * D * sizeof(unsigned short);
    unsigned short* Xb = (unsigned short*)(ws + off);          // N*64 bf16  (1 MB)
    off += (size_t)N * D * sizeof(unsigned short);
    float* t = (float*)(ws + off);                             // M floats (128 KB)
    off += (size_t)M * sizeof(float);
    float* sqx = (float*)(ws + off);                           // N floats (32 KB; also t's over-read pad)
    off += (size_t)N * sizeof(float);
    float* partial = (float*)(ws + off);                       // N*SPLITS (1 MB)
    off += (size_t)N * SPLITS * sizeof(float);
    float* psum_arr = (float*)(ws + off);                      // 64 floats

    prep<<<(M >> 4) + (N >> 4) + 64, 256, 0, stream>>>(X, Y, psi, Xb, Yb, t, sqx, psum_arr, N, M);
    // block = 4 waves x (G*16) rows = 256 source rows -> grid = (32, N/256) = 1024 blocks
    sdot_main<<<dim3(SPLITS, N / 256), 256, 0, stream>>>(Xb, Yb, t, partial, M);
    finalize<<<N / 4, 256, 0, stream>>>(sqx, partial, psum_arr, out, M);
}

// Round 10
// 102.718 us; speedup vs baseline: 1.0338x; 1.0036x over previous
//
#include <hip/hip_runtime.h>
#include <stdint.h>

typedef float  f32x4v __attribute__((ext_vector_type(4)));
typedef short  s16x8  __attribute__((ext_vector_type(8)));

constexpr int D      = 64;    // feature dim (fixed by problem)
constexpr int SPLITS = 32;    // M-chunks; grid = (32, N/512) = 512 blocks = 2/CU
constexpr int TILE_M = 128;   // targets staged in LDS per tile (double-buffered)
constexpr int G      = 8;     // source groups of 16 per wave -> 128 src/wave, 512/block

__device__ __forceinline__ unsigned short f2bf(float f) {
    // round-to-nearest-even fp32 -> bf16 (inputs are finite normals)
    unsigned int u = __float_as_uint(f);
    u = (u + 0x7FFFu + ((u >> 16) & 1u)) >> 16;
    return (unsigned short)u;
}

// async global->LDS DMA; LDS dest is wave-uniform base + lane*size (linear),
// swizzle applied on the per-lane GLOBAL source address instead.
__device__ __forceinline__ void gload_lds16(const void* g, void* l) {
    __builtin_amdgcn_global_load_lds((__attribute__((address_space(1))) void*)g,
                                     (__attribute__((address_space(3))) void*)l, 16, 0, 0);
}
__device__ __forceinline__ void gload_lds4(const void* g, void* l) {
    __builtin_amdgcn_global_load_lds((__attribute__((address_space(1))) void*)g,
                                     (__attribute__((address_space(3))) void*)l, 4, 0, 0);
}

// ---- fused prep (one launch):
//  blocks [0, M/16)            : Yb = bf16(Y),      t[m]  = ||y||^2 - psi[m]
//  blocks [M/16, M/16+N/16)    : Xb = bf16(-2*X),   sqx[n] = ||x||^2
//  blocks [.., +64)            : psi partial sums -> psum_arr[64]
__global__ __launch_bounds__(256)
void prep(const float* __restrict__ X, const float* __restrict__ Y,
          const float* __restrict__ psi,
          unsigned short* __restrict__ Xb, unsigned short* __restrict__ Yb,
          float* __restrict__ t, float* __restrict__ sqx,
          float* __restrict__ psum_arr, int N, int M) {
    const int tid  = threadIdx.x;
    const int lane = tid & 63, wave = tid >> 6;
    const int r16  = lane & 15, q = lane >> 4;
    const int NYB = M >> 4, NXB = N >> 4;
    const int b = blockIdx.x;
    __shared__ float red[4];

    if (b < NYB) {
        const int row = b * 16 + wave * 4 + q;
        const float4 v = *reinterpret_cast<const float4*>(Y + (size_t)row * D + r16 * 4);
        uint2 p;
        p.x = (unsigned)f2bf(v.x) | ((unsigned)f2bf(v.y) << 16);
        p.y = (unsigned)f2bf(v.z) | ((unsigned)f2bf(v.w) << 16);
        *reinterpret_cast<uint2*>(Yb + (size_t)row * D + r16 * 4) = p;
        float s = v.x * v.x + v.y * v.y + v.z * v.z + v.w * v.w;
        #pragma unroll
        for (int off = 1; off <= 8; off <<= 1) s += __shfl_xor(s, off);
        if (r16 == 0) t[row] = s - psi[row];
    } else if (b < NYB + NXB) {
        const int row = (b - NYB) * 16 + wave * 4 + q;
        const float4 v = *reinterpret_cast<const float4*>(X + (size_t)row * D + r16 * 4);
        uint2 p;   // store -2*x in bf16: cost = (||y||^2 - psi) + <-2x, y>
        p.x = (unsigned)f2bf(-2.f * v.x) | ((unsigned)f2bf(-2.f * v.y) << 16);
        p.y = (unsigned)f2bf(-2.f * v.z) | ((unsigned)f2bf(-2.f * v.w) << 16);
        *reinterpret_cast<uint2*>(Xb + (size_t)row * D + r16 * 4) = p;
        float s = v.x * v.x + v.y * v.y + v.z * v.z + v.w * v.w;
        #pragma unroll
        for (int off = 1; off <= 8; off <<= 1) s += __shfl_xor(s, off);
        if (r16 == 0) sqx[row] = s;
    } else {
        const int g = b - NYB - NXB;            // 0..63, M == 64*512
        float s = psi[g * 512 + tid] + psi[g * 512 + 256 + tid];
        #pragma unroll
        for (int off = 1; off <= 32; off <<= 1) s += __shfl_xor(s, off);
        if (lane == 0) red[wave] = s;
        __syncthreads();
        if (tid == 0) psum_arr[g] = red[0] + red[1] + red[2] + red[3];
    }
}

// ---- main: A = targets (LDS), B = sources (registers), 16x16x32 bf16 MFMA.
// R2's proven lockstep streaming skeleton (TILE_M=128 dbuf, stage->compute->
// vmcnt0->barrier per tile) with the pipe-balance fix from R9's counters:
//  - G=8: 3 ds_read_b128 feed 16 MFMAs -> LDS demand 46% of MFMA pipe time
//    (R9's G=4 was 93% -> LDS co-saturated and every pipe jammed at ~33%).
//  - __launch_bounds__(256,2): unified VGPR budget 256 -> b[8][2]=64 +
//    accA/accB=64 + rmin/a/tv/addr (~155 total) provably CANNOT spill.
//    (R3/R5/R6 big-G attempts all spilled under 64-128 caps; never clean.)
//  - ping-pong accA/accB deferred fold: fold reads accs completed a full
//    step earlier -> no MFMA-latency RAW stall on the issue stream.
// C/D: col=lane&15 -> SOURCE, row=(lane>>4)*4+r -> TARGET: min axis in-register;
// tv = ||y||^2 - psi enters as the MFMA C-operand (one f32x4 ds_read).
__global__ __launch_bounds__(256, 2)
void sdot_main(const unsigned short* __restrict__ Xb,
               const unsigned short* __restrict__ Yb,
               const float* __restrict__ t,
               float* __restrict__ partial, int M) {
    __shared__ __align__(16) unsigned short ly[2][TILE_M * 64]; // 2 x 16 KB
    __shared__ __align__(16) float lt[2][256];                  // 2 x 1 KB (128 used)

    const int tid  = threadIdx.x;
    const int wave = tid >> 6, lane = tid & 63;
    const int quad = lane >> 4, r16 = lane & 15;
    const int chunk  = blockIdx.x;
    const int rowgrp = blockIdx.y;
    const int CH      = M / SPLITS;         // 1024
    const int m_begin = chunk * CH;
    const int NTT     = CH / TILE_M;        // 8 tiles

    // B fragments: sources in regs. B[n=lane&15][k=quad*8+j], K-half h.
    // 4 waves x G*16 = 512 source rows per block.
    s16x8 b[G][2];
    #pragma unroll
    for (int g = 0; g < G; ++g) {
        const int srow = rowgrp * 512 + wave * (G * 16) + g * 16 + r16;
        #pragma unroll
        for (int h = 0; h < 2; ++h)
            b[g][h] = *reinterpret_cast<const s16x8*>(Xb + (size_t)srow * D + h * 32 + quad * 8);
    }

    float rmin[G];
    #pragma unroll
    for (int g = 0; g < G; ++g) rmin[g] = 1e30f;

    // stage one tile: 16 KB Yb (4 x 16B DMA/thread; source pre-swizzled so linear
    // LDS slot c holds logical granule c^(row&7)) + t values into lt.
    auto stage = [&](int buf, int mb) {
        #pragma unroll
        for (int i = 0; i < 4; ++i) {
            const int idx = i * 256 + tid;     // granule index (8 ushorts each)
            const int row = idx >> 3, c = idx & 7;
            gload_lds16(Yb + (size_t)(mb + row) * D + ((c ^ (row & 7)) << 3),
                        &ly[buf][(i * 256 + wave * 64) << 3]);
        }
        // waves 2,3 land in lt[128..255] (t over-read past M hits sqx region: harmless)
        gload_lds4(t + mb + wave * 64 + lane, &lt[buf][wave * 64]);
    };

    stage(0, m_begin);
    asm volatile("s_waitcnt vmcnt(0)" ::: "memory");
    __builtin_amdgcn_s_barrier();

    const int csw0 = (quad ^ (r16 & 7)) << 3;        // st-invariant swizzled cols
    const int csw1 = ((quad + 4) ^ (r16 & 7)) << 3;

    // STEP: issue 16 MFMAs for step 'st' of the current tile into acc set A_.
#define SDOT_STEP(st, A_)                                                           \
    {                                                                               \
        const int trow = (st) * 16 + r16;                                           \
        const s16x8 a0 = *reinterpret_cast<const s16x8*>(&ly[buf][trow * 64 + csw0]); \
        const s16x8 a1 = *reinterpret_cast<const s16x8*>(&ly[buf][trow * 64 + csw1]); \
        const f32x4v tv4 = *reinterpret_cast<const f32x4v*>(&lt[buf][(st) * 16 + quad * 4]); \
        __builtin_amdgcn_s_setprio(1);                                              \
        _Pragma("unroll")                                                           \
        for (int g = 0; g < G; ++g)                                                 \
            A_[g] = __builtin_amdgcn_mfma_f32_16x16x32_bf16(a0, b[g][0], tv4, 0, 0, 0); \
        _Pragma("unroll")                                                           \
        for (int g = 0; g < G; ++g)                                                 \
            A_[g] = __builtin_amdgcn_mfma_f32_16x16x32_bf16(a1, b[g][1], A_[g], 0, 0, 0); \
        __builtin_amdgcn_s_setprio(0);                                              \
    }
    // FOLD: min-reduce a COMPLETED acc set into rmin (issued a full step earlier)
#define SDOT_FOLD(A_)                                                               \
    {                                                                               \
        _Pragma("unroll")                                                           \
        for (int g = 0; g < G; ++g)                                                 \
            rmin[g] = fminf(fminf(fminf(A_[g][0], A_[g][1]),                        \
                                  fminf(A_[g][2], A_[g][3])), rmin[g]);             \
    }

    f32x4v accA[G], accB[G];
    for (int tI = 0; tI < NTT; ++tI) {
        const int buf = tI & 1;
        if (tI + 1 < NTT) stage(buf ^ 1, m_begin + (tI + 1) * TILE_M);

        // 8 steps over the tile, ping-pong deferred fold
        SDOT_STEP(0, accB);
        #pragma unroll
        for (int p = 0; p < 3; ++p) {            // steps 1..6
            SDOT_STEP(2 * p + 1, accA);  SDOT_FOLD(accB);
            SDOT_STEP(2 * p + 2, accB);  SDOT_FOLD(accA);
        }
        SDOT_STEP(7, accA);  SDOT_FOLD(accB);  SDOT_FOLD(accA);

        // next-tile DMA flew under the MFMAs; drain + barrier, swap buffers.
        asm volatile("s_waitcnt vmcnt(0)" ::: "memory");
        __builtin_amdgcn_s_barrier();
    }
#undef SDOT_STEP
#undef SDOT_FOLD

    // min across the 4 row-block lane groups (lanes l, l^16, l^32, l^48 share col)
    #pragma unroll
    for (int off = 16; off <= 32; off <<= 1)
        #pragma unroll
        for (int g = 0; g < G; ++g)
            rmin[g] = fminf(rmin[g], __shfl_xor(rmin[g], off));

    if (quad == 0) {   // lanes 0..15: col n = r16
        #pragma unroll
        for (int g = 0; g < G; ++g) {
            const int row = rowgrp * 512 + wave * (G * 16) + g * 16 + r16;
            partial[(size_t)row * SPLITS + chunk] = rmin[g];
        }
    }
}

// ---- finalize: out[n] = ||x_n||^2 + mean(psi) + min over SPLITS partials
__global__ __launch_bounds__(256)
void finalize(const float* __restrict__ sqx, const float* __restrict__ partial,
              const float* __restrict__ psum_arr, float* __restrict__ out, int M) {
    const int lane = threadIdx.x & 63, wave = threadIdx.x >> 6;
    const int row  = blockIdx.x * 4 + wave;
    float ps = psum_arr[lane];                 // 64 partial psi sums
    #pragma unroll
    for (int off = 1; off <= 32; off <<= 1) ps += __shfl_xor(ps, off);
    float pm = (lane < SPLITS) ? partial[(size_t)row * SPLITS + lane] : 1e30f;
    #pragma unroll
    for (int off = 1; off <= 32; off <<= 1) pm = fminf(pm, __shfl_xor(pm, off));
    if (lane == 0) out[row] = sqx[row] + ps / (float)M + pm;
}

extern "C" void kernel_launch(void* const* d_in, const int* in_sizes, int n_in,
                              void* d_out, int out_size, void* d_ws, size_t ws_size,
                              hipStream_t stream) {
    const float* X   = (const float*)d_in[0];   // [N, 64]
    const float* Y   = (const float*)d_in[1];   // [M, 64]
    const float* psi = (const float*)d_in[2];   // [M]
    float* out = (float*)d_out;

    const int N = in_sizes[0] / D;   // 8192
    const int M = in_sizes[2];       // 32768

    char* ws = (char*)d_ws;
    unsigned short* Yb = (unsigned short*)ws;                  // M*64 bf16  (4 MB)
    size_t off = (size_t)M * D * sizeof(unsigned short);
    unsigned short* Xb = (unsigned short*)(ws + off);          // N*64 bf16  (1 MB)
    off += (size_t)N * D * sizeof(unsigned short);
    float* t = (float*)(ws + off);                             // M floats (128 KB)
    off += (size_t)M * sizeof(float);
    float* sqx = (float*)(ws + off);                           // N floats (32 KB; also t's over-read pad)
    off += (size_t)N * sizeof(float);
    float* partial = (float*)(ws + off);                       // N*SPLITS (1 MB)
    off += (size_t)N * SPLITS * sizeof(float);
    float* psum_arr = (float*)(ws + off);                      // 64 floats

    prep<<<(M >> 4) + (N >> 4) + 64, 256, 0, stream>>>(X, Y, psi, Xb, Yb, t, sqx, psum_arr, N, M);
    // block = 4 waves x (G*16) rows = 512 source rows -> grid = (32, N/512) = 512 blocks
    sdot_main<<<dim3(SPLITS, N / 512), 256, 0, stream>>>(Xb, Yb, t, partial, M);
    finalize<<<N / 4, 256, 0, stream>>>(sqx, partial, psum_arr, out, M);
}

// Round 11
// 102.620 us; speedup vs baseline: 1.0348x; 1.0010x over previous
//
#include <hip/hip_runtime.h>
#include <stdint.h>

typedef float  f32x4v __attribute__((ext_vector_type(4)));
typedef short  s16x8  __attribute__((ext_vector_type(8)));

constexpr int D      = 64;    // feature dim (fixed by problem)
constexpr int SPLITS = 32;    // M-chunks; grid = (32, N/512) = 512 blocks = 2/CU
constexpr int TILE_M = 128;   // targets staged in LDS per tile (double-buffered)
constexpr int G      = 8;     // source groups of 16 per wave -> 128 src/wave, 512/block

__device__ __forceinline__ unsigned short f2bf(float f) {
    // round-to-nearest-even fp32 -> bf16 (inputs are finite normals)
    unsigned int u = __float_as_uint(f);
    u = (u + 0x7FFFu + ((u >> 16) & 1u)) >> 16;
    return (unsigned short)u;
}

// async global->LDS DMA; LDS dest is wave-uniform base + lane*size (linear),
// swizzle applied on the per-lane GLOBAL source address instead.
__device__ __forceinline__ void gload_lds16(const void* g, void* l) {
    __builtin_amdgcn_global_load_lds((__attribute__((address_space(1))) void*)g,
                                     (__attribute__((address_space(3))) void*)l, 16, 0, 0);
}
__device__ __forceinline__ void gload_lds4(const void* g, void* l) {
    __builtin_amdgcn_global_load_lds((__attribute__((address_space(1))) void*)g,
                                     (__attribute__((address_space(3))) void*)l, 4, 0, 0);
}

// ---- fused prep (one launch):
//  blocks [0, M/16)            : Yb = bf16(Y),      t[m]  = ||y||^2 - psi[m]
//  blocks [M/16, M/16+N/16)    : Xb = bf16(-2*X),   sqx[n] = ||x||^2
//  blocks [.., +64)            : psi partial sums -> psum_arr[64]
__global__ __launch_bounds__(256)
void prep(const float* __restrict__ X, const float* __restrict__ Y,
          const float* __restrict__ psi,
          unsigned short* __restrict__ Xb, unsigned short* __restrict__ Yb,
          float* __restrict__ t, float* __restrict__ sqx,
          float* __restrict__ psum_arr, int N, int M) {
    const int tid  = threadIdx.x;
    const int lane = tid & 63, wave = tid >> 6;
    const int r16  = lane & 15, q = lane >> 4;
    const int NYB = M >> 4, NXB = N >> 4;
    const int b = blockIdx.x;
    __shared__ float red[4];

    if (b < NYB) {
        const int row = b * 16 + wave * 4 + q;
        const float4 v = *reinterpret_cast<const float4*>(Y + (size_t)row * D + r16 * 4);
        uint2 p;
        p.x = (unsigned)f2bf(v.x) | ((unsigned)f2bf(v.y) << 16);
        p.y = (unsigned)f2bf(v.z) | ((unsigned)f2bf(v.w) << 16);
        *reinterpret_cast<uint2*>(Yb + (size_t)row * D + r16 * 4) = p;
        float s = v.x * v.x + v.y * v.y + v.z * v.z + v.w * v.w;
        #pragma unroll
        for (int off = 1; off <= 8; off <<= 1) s += __shfl_xor(s, off);
        if (r16 == 0) t[row] = s - psi[row];
    } else if (b < NYB + NXB) {
        const int row = (b - NYB) * 16 + wave * 4 + q;
        const float4 v = *reinterpret_cast<const float4*>(X + (size_t)row * D + r16 * 4);
        uint2 p;   // store -2*x in bf16: cost = (||y||^2 - psi) + <-2x, y>
        p.x = (unsigned)f2bf(-2.f * v.x) | ((unsigned)f2bf(-2.f * v.y) << 16);
        p.y = (unsigned)f2bf(-2.f * v.z) | ((unsigned)f2bf(-2.f * v.w) << 16);
        *reinterpret_cast<uint2*>(Xb + (size_t)row * D + r16 * 4) = p;
        float s = v.x * v.x + v.y * v.y + v.z * v.z + v.w * v.w;
        #pragma unroll
        for (int off = 1; off <= 8; off <<= 1) s += __shfl_xor(s, off);
        if (r16 == 0) sqx[row] = s;
    } else {
        const int g = b - NYB - NXB;            // 0..63, M == 64*512
        float s = psi[g * 512 + tid] + psi[g * 512 + 256 + tid];
        #pragma unroll
        for (int off = 1; off <= 32; off <<= 1) s += __shfl_xor(s, off);
        if (lane == 0) red[wave] = s;
        __syncthreads();
        if (tid == 0) psum_arr[g] = red[0] + red[1] + red[2] + red[3];
    }
}

// ---- main: A = targets (LDS), B = sources (registers), 16x16x32 bf16 MFMA.
// R10 skeleton (TILE_M=128 dbuf, stage->compute->vmcnt0->barrier per tile,
// G=8, launch_bounds(256,2): ~184 unified VGPR <= 256, no spill) with the
// R10-counter-diagnosed fix:
//  - NO s_setprio. It is an SALU intrinsic with unmodeled side effects -> a
//    compiler scheduling FENCE: ds_reads could never be hoisted across step
//    boundaries, exposing full LDS latency + lgkmcnt(0) before every MFMA
//    burst (per-wave MFMA duty ~34% == measured MfmaUtil across R4-R10).
//  - Explicit one-step-ahead ds_read prefetch into rotating named registers:
//    step k+1's a0/a1/tv issue BEFORE step k's MFMA burst, so lgkm is already
//    satisfied when k+1's MFMAs need them. Hand-unrolled 8-step tile body.
//  - Ping-pong accA/accB deferred fold kept (fold trails the burst by 1 step).
// C/D: col=lane&15 -> SOURCE, row=(lane>>4)*4+r -> TARGET: min axis in-register;
// tv = ||y||^2 - psi enters as the MFMA C-operand (one f32x4 ds_read).
__global__ __launch_bounds__(256, 2)
void sdot_main(const unsigned short* __restrict__ Xb,
               const unsigned short* __restrict__ Yb,
               const float* __restrict__ t,
               float* __restrict__ partial, int M) {
    __shared__ __align__(16) unsigned short ly[2][TILE_M * 64]; // 2 x 16 KB
    __shared__ __align__(16) float lt[2][256];                  // 2 x 1 KB (128 used)

    const int tid  = threadIdx.x;
    const int wave = tid >> 6, lane = tid & 63;
    const int quad = lane >> 4, r16 = lane & 15;
    const int chunk  = blockIdx.x;
    const int rowgrp = blockIdx.y;
    const int CH      = M / SPLITS;         // 1024
    const int m_begin = chunk * CH;
    const int NTT     = CH / TILE_M;        // 8 tiles

    // B fragments: sources in regs. B[n=lane&15][k=quad*8+j], K-half h.
    // 4 waves x G*16 = 512 source rows per block.
    s16x8 b[G][2];
    #pragma unroll
    for (int g = 0; g < G; ++g) {
        const int srow = rowgrp * 512 + wave * (G * 16) + g * 16 + r16;
        #pragma unroll
        for (int h = 0; h < 2; ++h)
            b[g][h] = *reinterpret_cast<const s16x8*>(Xb + (size_t)srow * D + h * 32 + quad * 8);
    }

    float rmin[G];
    #pragma unroll
    for (int g = 0; g < G; ++g) rmin[g] = 1e30f;

    // stage one tile: 16 KB Yb (4 x 16B DMA/thread; source pre-swizzled so linear
    // LDS slot c holds logical granule c^(row&7)) + t values into lt.
    auto stage = [&](int buf, int mb) {
        #pragma unroll
        for (int i = 0; i < 4; ++i) {
            const int idx = i * 256 + tid;     // granule index (8 ushorts each)
            const int row = idx >> 3, c = idx & 7;
            gload_lds16(Yb + (size_t)(mb + row) * D + ((c ^ (row & 7)) << 3),
                        &ly[buf][(i * 256 + wave * 64) << 3]);
        }
        // waves 2,3 land in lt[128..255] (t over-read past M hits sqx region: harmless)
        gload_lds4(t + mb + wave * 64 + lane, &lt[buf][wave * 64]);
    };

    stage(0, m_begin);
    asm volatile("s_waitcnt vmcnt(0)" ::: "memory");
    __builtin_amdgcn_s_barrier();

    const int csw0 = (quad ^ (r16 & 7)) << 3;        // st-invariant swizzled cols
    const int csw1 = ((quad + 4) ^ (r16 & 7)) << 3;

    // READ: issue the 3 LDS reads for step 'st' into named regs (no use here ->
    // no lgkm wait emitted at this point; latency hides under the next burst).
#define SDOT_READ(st, A0_, A1_, TV_)                                                \
    {                                                                               \
        const int trow = (st) * 16 + r16;                                           \
        A0_ = *reinterpret_cast<const s16x8*>(&ly[buf][trow * 64 + csw0]);          \
        A1_ = *reinterpret_cast<const s16x8*>(&ly[buf][trow * 64 + csw1]);          \
        TV_ = *reinterpret_cast<const f32x4v*>(&lt[buf][(st) * 16 + quad * 4]);     \
    }
    // MFMA: 16 MFMAs on already-resident regs into acc set A_ (no setprio fence).
#define SDOT_MFMA(A0_, A1_, TV_, A_)                                                \
    {                                                                               \
        _Pragma("unroll")                                                           \
        for (int g = 0; g < G; ++g)                                                 \
            A_[g] = __builtin_amdgcn_mfma_f32_16x16x32_bf16(A0_, b[g][0], TV_, 0, 0, 0); \
        _Pragma("unroll")                                                           \
        for (int g = 0; g < G; ++g)                                                 \
            A_[g] = __builtin_amdgcn_mfma_f32_16x16x32_bf16(A1_, b[g][1], A_[g], 0, 0, 0); \
    }
    // FOLD: min-reduce a COMPLETED acc set into rmin (issued a full step earlier)
#define SDOT_FOLD(A_)                                                               \
    {                                                                               \
        _Pragma("unroll")                                                           \
        for (int g = 0; g < G; ++g)                                                 \
            rmin[g] = fminf(fminf(fminf(A_[g][0], A_[g][1]),                        \
                                  fminf(A_[g][2], A_[g][3])), rmin[g]);             \
    }
#define SDOT_ROT  { a0 = n0; a1 = n1; tv = nv; }

    f32x4v accA[G], accB[G];
    s16x8  a0, a1, n0, n1;
    f32x4v tv, nv;

    for (int tI = 0; tI < NTT; ++tI) {
        const int buf = tI & 1;
        if (tI + 1 < NTT) stage(buf ^ 1, m_begin + (tI + 1) * TILE_M);

        // 8 steps, hand-unrolled: READ(k+1) || MFMA(k) || FOLD(k-1)
        SDOT_READ(0, a0, a1, tv);
        SDOT_READ(1, n0, n1, nv);  SDOT_MFMA(a0, a1, tv, accB);                   SDOT_ROT;
        SDOT_READ(2, n0, n1, nv);  SDOT_MFMA(a0, a1, tv, accA);  SDOT_FOLD(accB); SDOT_ROT;
        SDOT_READ(3, n0, n1, nv);  SDOT_MFMA(a0, a1, tv, accB);  SDOT_FOLD(accA); SDOT_ROT;
        SDOT_READ(4, n0, n1, nv);  SDOT_MFMA(a0, a1, tv, accA);  SDOT_FOLD(accB); SDOT_ROT;
        SDOT_READ(5, n0, n1, nv);  SDOT_MFMA(a0, a1, tv, accB);  SDOT_FOLD(accA); SDOT_ROT;
        SDOT_READ(6, n0, n1, nv);  SDOT_MFMA(a0, a1, tv, accA);  SDOT_FOLD(accB); SDOT_ROT;
        SDOT_READ(7, n0, n1, nv);  SDOT_MFMA(a0, a1, tv, accB);  SDOT_FOLD(accA); SDOT_ROT;
                                   SDOT_MFMA(a0, a1, tv, accA);  SDOT_FOLD(accB);
        SDOT_FOLD(accA);

        // next-tile DMA flew under the MFMAs; drain + barrier, swap buffers.
        asm volatile("s_waitcnt vmcnt(0)" ::: "memory");
        __builtin_amdgcn_s_barrier();
    }
#undef SDOT_READ
#undef SDOT_MFMA
#undef SDOT_FOLD
#undef SDOT_ROT

    // min across the 4 row-block lane groups (lanes l, l^16, l^32, l^48 share col)
    #pragma unroll
    for (int off = 16; off <= 32; off <<= 1)
        #pragma unroll
        for (int g = 0; g < G; ++g)
            rmin[g] = fminf(rmin[g], __shfl_xor(rmin[g], off));

    if (quad == 0) {   // lanes 0..15: col n = r16
        #pragma unroll
        for (int g = 0; g < G; ++g) {
            const int row = rowgrp * 512 + wave * (G * 16) + g * 16 + r16;
            partial[(size_t)row * SPLITS + chunk] = rmin[g];
        }
    }
}

// ---- finalize: out[n] = ||x_n||^2 + mean(psi) + min over SPLITS partials
__global__ __launch_bounds__(256)
void finalize(const float* __restrict__ sqx, const float* __restrict__ partial,
              const float* __restrict__ psum_arr, float* __restrict__ out, int M) {
    const int lane = threadIdx.x & 63, wave = threadIdx.x >> 6;
    const int row  = blockIdx.x * 4 + wave;
    float ps = psum_arr[lane];                 // 64 partial psi sums
    #pragma unroll
    for (int off = 1; off <= 32; off <<= 1) ps += __shfl_xor(ps, off);
    float pm = (lane < SPLITS) ? partial[(size_t)row * SPLITS + lane] : 1e30f;
    #pragma unroll
    for (int off = 1; off <= 32; off <<= 1) pm = fminf(pm, __shfl_xor(pm, off));
    if (lane == 0) out[row] = sqx[row] + ps / (float)M + pm;
}

extern "C" void kernel_launch(void* const* d_in, const int* in_sizes, int n_in,
                              void* d_out, int out_size, void* d_ws, size_t ws_size,
                              hipStream_t stream) {
    const float* X   = (const float*)d_in[0];   // [N, 64]
    const float* Y   = (const float*)d_in[1];   // [M, 64]
    const float* psi = (const float*)d_in[2];   // [M]
    float* out = (float*)d_out;

    const int N = in_sizes[0] / D;   // 8192
    const int M = in_sizes[2];       // 32768

    char* ws = (char*)d_ws;
    unsigned short* Yb = (unsigned short*)ws;                  // M*64 bf16  (4 MB)
    size_t off = (size_t)M * D * sizeof(unsigned short);
    unsigned short* Xb = (unsigned short*)(ws + off);          // N*64 bf16  (1 MB)
    off += (size_t)N * D * sizeof(unsigned short);
    float* t = (float*)(ws + off);                             // M floats (128 KB)
    off += (size_t)M * sizeof(float);
    float* sqx = (float*)(ws + off);                           // N floats (32 KB; also t's over-read pad)
    off += (size_t)N * sizeof(float);
    float* partial = (float*)(ws + off);                       // N*SPLITS (1 MB)
    off += (size_t)N * SPLITS * sizeof(float);
    float* psum_arr = (float*)(ws + off);                      // 64 floats

    prep<<<(M >> 4) + (N >> 4) + 64, 256, 0, stream>>>(X, Y, psi, Xb, Yb, t, sqx, psum_arr, N, M);
    // block = 4 waves x (G*16) rows = 512 source rows -> grid = (32, N/512) = 512 blocks
    sdot_main<<<dim3(SPLITS, N / 512), 256, 0, stream>>>(Xb, Yb, t, partial, M);
    finalize<<<N / 4, 256, 0, stream>>>(sqx, partial, psum_arr, out, M);
}